// Round 18
// baseline (2237.504 us; speedup 1.0000x reference)
//
#include <hip/hip_runtime.h>
#include <hip/hip_bf16.h>
#include <math.h>

#define B_    64
#define T_    24
#define IND_  25
#define HID_  64
#define NPIX  625

// padded-grid geometry
#define WP0   27
#define WP1   29
#define HSTR  72          // h-buf pixel stride (ushorts)
#define HROWS0 832
#define HROWS1 944
#define HB0   (HROWS0*HSTR)
#define HB1   (HROWS1*HSTR)
#define HB0T  (B_*HB0)
#define HB1T  (B_*HB1)
#define HPART (HB0T+HB1T)

// universal x buffer: 2-halo 29-wide grid, row stride padded to 936 ush
#define WPX   29
#define XRW   936
#define XROWSU 34
#define XBU   (XROWSU*XRW)    // 31,824 ush per (par,b)
#define XBUT  (B_*XBU)        // 2,036,736 per parity

// 4-row rowgroups: 7 per plane (rows {4,4,4,4,4,4,1})
#define NRG   7
#define RST0  172
#define RST1  240
#define CH0   (RST0*9)    // 1548 h chunks
#define CH1   (RST1*9)    // 2160
#define XTROWS 10
#define XTCH  (XTROWS*XRW/8)  // 1170 x chunks

// final-conv combined input: [b][832 rows][128] bf16
#define HCROWS 832
#define HCB    (HCROWS*128)
#define HCTOT  (B_*HCB)

#define WFRAG_PER_BR (9*3*4*4*512)    // 221,184
#define WFRAG_TOT    (2*WFRAG_PER_BR)

typedef __bf16 bf16x8 __attribute__((ext_vector_type(8)));
typedef float  f32x4  __attribute__((ext_vector_type(4)));
typedef _Float16 f16x4 __attribute__((ext_vector_type(4)));
typedef unsigned short ushort_t;
typedef unsigned int   uint_t;

typedef const __attribute__((address_space(1))) void as1_cvoid;
typedef __attribute__((address_space(3))) void as3_void;

__device__ __forceinline__ float sigmoidf_(float x) { return 1.f / (1.f + __expf(-x)); }
__device__ __forceinline__ float tanh_fast(float x) { return 2.f / (1.f + __expf(-2.f * x)) - 1.f; }
__device__ __forceinline__ ushort_t f2bf(float f) {
    unsigned int u = __float_as_uint(f);
    u += 0x7FFFu + ((u >> 16) & 1u);
    return (ushort_t)(u >> 16);
}

__global__ __launch_bounds__(256) void fill_zero_kernel(uint_t* __restrict__ p, int n) {
    int i = blockIdx.x * 256 + threadIdx.x;
    if (i < n) p[i] = 0u;
}

// Wfrag[br][tap][kk][wm][mf][lane][e]: m = wm*64 + gate*16 + ocl, gate=mf, oc=wm*16+l16.
__global__ __launch_bounds__(256) void repack_w_kernel(
    const float* __restrict__ w1, const float* __restrict__ w2, ushort_t* __restrict__ Wfrag)
{
    int id = blockIdx.x * 256 + threadIdx.x;
    if (id >= WFRAG_TOT) return;
    int e    = id & 7;
    int lane = (id >> 3) & 63;
    int mf   = (id >> 9) & 3;
    int wm   = (id >> 11) & 3;
    int rest = id >> 13;
    int kk   = rest % 3;
    int tap  = (rest / 3) % 9;
    int br   = rest / 27;
    int l16 = lane & 15, kh = lane >> 4;
    int gate = mf;
    int oc   = wm * 16 + l16;
    int k    = kh * 8 + e;
    int c;
    if (kk == 0)      c = (k < IND_) ? k : -1;
    else if (kk == 1) c = IND_ + k;
    else              c = IND_ + 32 + k;
    const float* w = br ? w2 : w1;
    float v = (c >= 0) ? w[((size_t)(gate * 64 + oc) * 89 + c) * 9 + tap] : 0.f;
    Wfrag[id] = f2bf(v);
}

__global__ __launch_bounds__(256) void repack_wc_kernel(
    const float* __restrict__ wc, ushort_t* __restrict__ Wc)
{
    int id = blockIdx.x * 256 + threadIdx.x;
    if (id >= 9 * 64 * 128) return;
    int k   = id % 128;
    int oc  = (id / 128) % 64;
    int tap = id / (128 * 64);
    Wc[id] = f2bf(wc[((size_t)(oc * 128) + k) * 9 + tap]);
}

// Standalone LN (only for t = 0; writes parity-0 universal x-buf).
__global__ __launch_bounds__(256) void ln_t_kernel(
    const float* __restrict__ x, const float* __restrict__ gamma, const float* __restrict__ beta,
    ushort_t* __restrict__ xbu, int t)
{
    int p = blockIdx.x * 256 + threadIdx.x;
    if (p >= B_ * NPIX) return;
    int b = p / NPIX, hw = p % NPIX;
    int y = hw / 25, xx = hw % 25;
    const float* xp = x + ((size_t)(b * T_ + t) * IND_) * NPIX + hw;
    float v[IND_];
    float s = 0.f;
#pragma unroll
    for (int c = 0; c < IND_; ++c) { v[c] = xp[c * NPIX]; s += v[c]; }
    float mu = s * (1.f / IND_);
    float ss = 0.f;
#pragma unroll
    for (int c = 0; c < IND_; ++c) { float d = v[c] - mu; ss += d * d; }
    float rstd = rsqrtf(ss * (1.f / IND_) + 1e-5f);
    ushort_t* o = xbu + (size_t)b * XBU + (size_t)(y + 2) * XRW + (size_t)(xx + 2) * 32;
#pragma unroll
    for (int c = 0; c < IND_; ++c)
        o[c] = f2bf((v[c] - mu) * rstd * gamma[c] + beta[c]);
}

// One ConvLSTM timestep, both branches. Uniform NF=4 (4-row groups, 64-AGPR acc),
// h+x tiles in LDS, fused LN(t+1), fp16 c. Grid 7x64x2 = 896 blocks (1.75 rounds @2/CU).
__global__ __launch_bounds__(512, 4) void convlstm_mfma_kernel(
    const float* __restrict__ x, const float* __restrict__ ln_g, const float* __restrict__ ln_b,
    ushort_t* __restrict__ xbu,
    const ushort_t* __restrict__ h0c, const ushort_t* __restrict__ h1c,
    ushort_t* __restrict__ h0n, ushort_t* __restrict__ h1n,
    const ushort_t* __restrict__ Wfrag,
    const float* __restrict__ bias1, const float* __restrict__ bias2,
    ushort_t* __restrict__ cst, int t)
{
    const int rg = blockIdx.x;
    const int b  = blockIdx.y;
    const int br = blockIdx.z;
    const int d  = 1 + br;
    const int Wp = 25 + 2 * d;
    const int par = t & 1, nxt = par ^ 1;
    const ushort_t* __restrict__ hc = (br ? h1c + (size_t)b * HB1 : h0c + (size_t)b * HB0);
    ushort_t* __restrict__ hn       = (br ? h1n + (size_t)b * HB1 : h0n + (size_t)b * HB0);
    const float* __restrict__ bias = br ? bias2 : bias1;
    const ushort_t* __restrict__ WFb = Wfrag + (size_t)br * WFRAG_PER_BR;
    f16x4* __restrict__ cb4 = (f16x4*)cst + (size_t)(br * B_ + b) * 16 * NPIX;

    __shared__ ushort_t tile[RST1 * HSTR];    // 34,560 B
    __shared__ ushort_t xt[XTROWS * XRW];     // 18,720 B

    const int tid = threadIdx.x;
    const int u0  = rg * 4 * Wp;
    const int CH  = br ? CH1 : CH0;
    const int wave_u = tid & 448;

    // ---- async stage h-tile (linear 16B chunks)
    {
        const char* gsrc = (const char*)(hc + (size_t)u0 * HSTR);
#pragma unroll
        for (int j = 0; j < 5; ++j) {
            const int i = j * 512 + tid;
            if (i < CH) {
                __builtin_amdgcn_global_load_lds(
                    (as1_cvoid*)(gsrc + (size_t)i * 16),
                    (as3_void*)((char*)tile + (size_t)(j * 512 + wave_u) * 16),
                    16, 0, 0);
            }
        }
    }
    // ---- async stage x-tile (10 universal rows, linear)
    {
        const char* gsrc = (const char*)(xbu + (size_t)par * XBUT + (size_t)b * XBU
                                         + (size_t)(rg * 4) * XRW);
#pragma unroll
        for (int j = 0; j < 3; ++j) {
            const int i = j * 512 + tid;
            if (i < XTCH) {
                __builtin_amdgcn_global_load_lds(
                    (as1_cvoid*)(gsrc + (size_t)i * 16),
                    (as3_void*)((char*)xt + (size_t)(j * 512 + wave_u) * 16),
                    16, 0, 0);
            }
        }
    }
    // ---- fused LN for step t+1 (single universal write; overlaps stage drain)
    if (t + 1 < T_ && tid < 45) {
        const int linbid = (br * B_ + b) * NRG + rg;
        const int p = linbid * 45 + tid;
        if (p < B_ * NPIX) {
            const int bb = p / NPIX, hw = p - bb * NPIX;
            const int y = hw / 25, xx = hw - y * 25;
            const float* xp = x + ((size_t)(bb * T_ + t + 1) * IND_) * NPIX + hw;
            float v[IND_];
            float s = 0.f;
#pragma unroll
            for (int c = 0; c < IND_; ++c) { v[c] = xp[c * NPIX]; s += v[c]; }
            const float mu = s * (1.f / IND_);
            float ss = 0.f;
#pragma unroll
            for (int c = 0; c < IND_; ++c) { float dd = v[c] - mu; ss += dd * dd; }
            const float rstd = rsqrtf(ss * (1.f / IND_) + 1e-5f);
            ushort_t us[IND_];
#pragma unroll
            for (int c = 0; c < IND_; ++c) us[c] = f2bf((v[c] - mu) * rstd * ln_g[c] + ln_b[c]);
            uint4 q0, q1, q2;
            q0.x = us[0] | ((uint_t)us[1] << 16);   q0.y = us[2] | ((uint_t)us[3] << 16);
            q0.z = us[4] | ((uint_t)us[5] << 16);   q0.w = us[6] | ((uint_t)us[7] << 16);
            q1.x = us[8] | ((uint_t)us[9] << 16);   q1.y = us[10] | ((uint_t)us[11] << 16);
            q1.z = us[12] | ((uint_t)us[13] << 16); q1.w = us[14] | ((uint_t)us[15] << 16);
            q2.x = us[16] | ((uint_t)us[17] << 16); q2.y = us[18] | ((uint_t)us[19] << 16);
            q2.z = us[20] | ((uint_t)us[21] << 16); q2.w = us[22] | ((uint_t)us[23] << 16);
            ushort_t* o = xbu + (size_t)nxt * XBUT + (size_t)bb * XBU
                          + (size_t)(y + 2) * XRW + (size_t)(xx + 2) * 32;
            *(uint4*)o = q0; *(uint4*)(o + 8) = q1; *(uint4*)(o + 16) = q2; o[24] = us[24];
        }
    }
    __syncthreads();

    const int w    = tid >> 6, lane = tid & 63;
    const int wm   = w & 3, wn = w >> 2;
    const int l16  = lane & 15, kh = lane >> 4;
    const int koff = kh * 8;

    f32x4 acc[4][4];
#pragma unroll
    for (int i = 0; i < 4; ++i)
#pragma unroll
        for (int j = 0; j < 4; ++j) acc[i][j] = (f32x4){0.f, 0.f, 0.f, 0.f};

    int baserel[4];   // h-tile relative (tile rows, width Wp)
    int basexl[4];    // x-tile relative (stride XRW), elem units
#pragma unroll
    for (int nf = 0; nf < 4; ++nf) {
        int n = wn * 64 + nf * 16 + l16;
        const int rit = n >> 5, xxa = n & 31;
        baserel[nf] = rit * Wp + xxa;
        basexl[nf]  = (rit + 2) * XRW + (xxa + 2) * 32 + koff;
    }

    const ushort_t* __restrict__ WTb = WFb + wm * 2048 + lane * 8;

#pragma unroll
    for (int u = 0; u < 27; ++u) {
        const int tap = u / 3, kk = u - 3 * (u / 3);
        const int ky = tap / 3, kx = tap - 3 * ky;
        bf16x8 af[4], bfr[4];
#pragma unroll
        for (int mf = 0; mf < 4; ++mf)
            af[mf] = *(const bf16x8*)(WTb + (size_t)u * 8192 + mf * 512);
        if (kk == 0) {
            const int toffx = ((ky - 1) * d) * XRW + ((kx - 1) * d) * 32;
#pragma unroll
            for (int nf = 0; nf < 4; ++nf)
                bfr[nf] = *(const bf16x8*)(xt + (size_t)(basexl[nf] + toffx));
        } else {
            const int toff = (ky * Wp + kx) * d;
#pragma unroll
            for (int nf = 0; nf < 4; ++nf)
                bfr[nf] = *(const bf16x8*)(tile + (baserel[nf] + toff) * HSTR
                                           + (kk - 1) * 32 + koff);
        }
#pragma unroll
        for (int mf = 0; mf < 4; ++mf)
#pragma unroll
            for (int nf = 0; nf < 4; ++nf)
                acc[mf][nf] = __builtin_amdgcn_mfma_f32_16x16x32_bf16(
                    af[mf], bfr[nf], acc[mf][nf], 0, 0, 0);
    }

    // Epilogue (c in fp16; bias loaded after the MFMA loop).
    const int oc0 = wm * 16 + kh * 4;
    const int ocq = wm * 4 + kh;
    float bi4[4], bf4[4], bo4[4], bg4[4];
#pragma unroll
    for (int r = 0; r < 4; ++r) {
        bi4[r] = bias[oc0 + r];
        bf4[r] = bias[64 + oc0 + r];
        bo4[r] = bias[128 + oc0 + r];
        bg4[r] = bias[192 + oc0 + r];
    }
#pragma unroll
    for (int nf = 0; nf < 4; ++nf) {
        const int n = wn * 64 + nf * 16 + l16;
        const int xx = n & 31;
        if (xx >= 25) continue;
        const int y = rg * 4 + (n >> 5);
        if (y >= 25) continue;
        const int pix = y * 25 + xx;
        f16x4* cp = cb4 + (size_t)ocq * NPIX + pix;
        f16x4 cvh;
        if (t != 0) cvh = *cp;
        else        cvh = (f16x4){0, 0, 0, 0};
        ushort_t hs[4];
#pragma unroll
        for (int r = 0; r < 4; ++r) {
            const float zi = acc[0][nf][r] + bi4[r];
            const float zf = acc[1][nf][r] + bf4[r];
            const float zo = acc[2][nf][r] + bo4[r];
            const float zg = acc[3][nf][r] + bg4[r];
            const float cn = sigmoidf_(zf) * (float)cvh[r] + sigmoidf_(zi) * tanh_fast(zg);
            cvh[r] = (_Float16)cn;
            hs[r] = f2bf(sigmoidf_(zo) * tanh_fast(cn));
        }
        *cp = cvh;
        uint2 hv;
        hv.x = (uint_t)hs[0] | ((uint_t)hs[1] << 16);
        hv.y = (uint_t)hs[2] | ((uint_t)hs[3] << 16);
        *(uint2*)(hn + (size_t)((y + d) * Wp + (xx + d)) * HSTR + oc0) = hv;
    }
}

// Combine final hidden states into Hc[b][(y+1)*27+(x+1)][k=128] bf16.
__global__ __launch_bounds__(256) void combine_h_kernel(
    const ushort_t* __restrict__ h0, const ushort_t* __restrict__ h1, ushort_t* __restrict__ Hc)
{
    int id = blockIdx.x * 256 + threadIdx.x;
    if (id >= B_ * NPIX * 128) return;
    int k   = id % 128;
    int pix = (id / 128) % NPIX;
    int b   = id / (128 * NPIX);
    int y = pix / 25, xx = pix % 25;
    ushort_t v;
    if (k < 64) v = h0[(size_t)b * HB0 + (size_t)((y + 1) * WP0 + (xx + 1)) * HSTR + k];
    else        v = h1[(size_t)b * HB1 + (size_t)((y + 2) * WP1 + (xx + 2)) * HSTR + (k - 64)];
    Hc[(size_t)b * HCB + (size_t)((y + 1) * 27 + (xx + 1)) * 128 + k] = v;
}

// Final 3x3 conv (128->64, pad 1) + bias + ReLU via MFMA implicit-GEMM.
__global__ __launch_bounds__(512) void conv_mfma_kernel(
    const ushort_t* __restrict__ Hc, const ushort_t* __restrict__ Wc,
    const float* __restrict__ bc, float* __restrict__ conv_out)
{
    const int rg = blockIdx.x;
    const int b  = blockIdx.y;
    const ushort_t* __restrict__ Hb = Hc + (size_t)b * HCB;

    const int tid  = threadIdx.x;
    const int w    = tid >> 6, lane = tid & 63;
    const int wm   = w & 1, wn = w >> 1;
    const int l16  = lane & 15, kh = lane >> 4;
    const int koff = kh * 8;

    f32x4 acc[2][2];
#pragma unroll
    for (int i = 0; i < 2; ++i)
#pragma unroll
        for (int j = 0; j < 2; ++j) acc[i][j] = (f32x4){0.f, 0.f, 0.f, 0.f};

    int baserow[2];
#pragma unroll
    for (int nf = 0; nf < 2; ++nf) {
        int n = wn * 32 + nf * 16 + l16;
        baserow[nf] = (rg * 4 + (n >> 5)) * 27 + (n & 31);
    }
    const ushort_t* __restrict__ Wm = Wc + (size_t)(wm * 32 + l16) * 128 + koff;

    for (int tap = 0; tap < 9; ++tap) {
        const int ky = tap / 3, kx = tap - 3 * ky;
        const int toff = ky * 27 + kx;
        const ushort_t* __restrict__ Wt = Wm + (size_t)tap * (64 * 128);
        const ushort_t* Urow[2];
#pragma unroll
        for (int nf = 0; nf < 2; ++nf)
            Urow[nf] = Hb + (size_t)(baserow[nf] + toff) * 128 + koff;
#pragma unroll
        for (int kk = 0; kk < 4; ++kk) {
            bf16x8 af[2], bfr[2];
#pragma unroll
            for (int mf = 0; mf < 2; ++mf)
                af[mf] = *(const bf16x8*)(Wt + mf * 16 * 128 + kk * 32);
#pragma unroll
            for (int nf = 0; nf < 2; ++nf)
                bfr[nf] = *(const bf16x8*)(Urow[nf] + kk * 32);
#pragma unroll
            for (int mf = 0; mf < 2; ++mf)
#pragma unroll
                for (int nf = 0; nf < 2; ++nf)
                    acc[mf][nf] = __builtin_amdgcn_mfma_f32_16x16x32_bf16(
                        af[mf], bfr[nf], acc[mf][nf], 0, 0, 0);
        }
    }

#pragma unroll
    for (int mf = 0; mf < 2; ++mf) {
#pragma unroll
        for (int nf = 0; nf < 2; ++nf) {
            const int n = wn * 32 + nf * 16 + l16;
            const int xx = n & 31;
            if (xx >= 25) continue;
            const int y = rg * 4 + wn;
            if (y >= 25) continue;
#pragma unroll
            for (int r = 0; r < 4; ++r) {
                const int oc = wm * 32 + mf * 16 + kh * 4 + r;
                const float v = fmaxf(acc[mf][nf][r] + bc[oc], 0.f);
                conv_out[((size_t)(b * 64 + oc)) * NPIX + y * 25 + xx] = v;
            }
        }
    }
}

__global__ __launch_bounds__(256) void pool_kernel(
    const float* __restrict__ conv_out, float* __restrict__ pool)
{
    int id = blockIdx.x * 256 + threadIdx.x;
    if (id >= B_ * 64 * 144) return;
    int px = id % 12;
    int py = (id / 12) % 12;
    int oc = (id / 144) % 64;
    int b  = id / (144 * 64);
    const float* p = conv_out + ((size_t)(b * 64 + oc)) * NPIX;
    const int cy = 2 * py, cx = 2 * px;
    float mx = fmaxf(fmaxf(p[cy * 25 + cx], p[cy * 25 + cx + 1]),
                     fmaxf(p[(cy + 1) * 25 + cx], p[(cy + 1) * 25 + cx + 1]));
    pool[(size_t)b * 9216 + oc * 144 + py * 12 + px] = mx;
}

__global__ __launch_bounds__(256) void fc1_kernel(
    const float* __restrict__ pool, const float* __restrict__ w1, const float* __restrict__ b1,
    float* __restrict__ f1)
{
    const int task = blockIdx.x * 4 + (threadIdx.x >> 6);
    const int lane = threadIdx.x & 63;
    const int b = task >> 6, oc = task & 63;
    const float* pr = pool + (size_t)b * 9216;
    const float* wr = w1 + (size_t)oc * 9216;
    float acc = 0.f;
#pragma unroll 4
    for (int it = 0; it < 36; ++it) {
        const int k = it * 256 + lane * 4;
        const float4 p = *(const float4*)(pr + k);
        const float4 ww = *(const float4*)(wr + k);
        acc += p.x * ww.x + p.y * ww.y + p.z * ww.z + p.w * ww.w;
    }
#pragma unroll
    for (int off = 32; off > 0; off >>= 1) acc += __shfl_down(acc, off);
    if (lane == 0) f1[b * 64 + oc] = fmaxf(acc + b1[oc], 0.f);
}

__global__ __launch_bounds__(64) void head2_kernel(
    const float* __restrict__ f1,
    const float* __restrict__ w2, const float* __restrict__ b2,
    const float* __restrict__ w3, const float* __restrict__ b3,
    float* __restrict__ out)
{
    const int b = blockIdx.x;
    __shared__ float f1l[64];
    __shared__ float f2[32];
    const int tid = threadIdx.x;
    f1l[tid] = f1[b * 64 + tid];
    __syncthreads();
    if (tid < 32) {
        float acc = b2[tid];
        const float* wr = w2 + (size_t)tid * 64;
#pragma unroll
        for (int k = 0; k < 64; ++k) acc += f1l[k] * wr[k];
        f2[tid] = fmaxf(acc, 0.f);
    }
    __syncthreads();
    if (tid == 0) {
        float y0 = b3[0], y1 = b3[1];
#pragma unroll
        for (int k = 0; k < 32; ++k) { y0 += f2[k] * w3[k]; y1 += f2[k] * w3[32 + k]; }
        const float m = fmaxf(y0, y1);
        const float lse = m + logf(expf(y0 - m) + expf(y1 - m));
        out[b * 2 + 0] = y0 - lse;
        out[b * 2 + 1] = y1 - lse;
    }
}

extern "C" void kernel_launch(void* const* d_in, const int* in_sizes, int n_in,
                              void* d_out, int out_size, void* d_ws, size_t ws_size,
                              hipStream_t stream) {
    const float* x    = (const float*)d_in[0];
    const float* ln_g = (const float*)d_in[1];
    const float* ln_b = (const float*)d_in[2];
    const float* w_l1 = (const float*)d_in[3];
    const float* b_l1 = (const float*)d_in[4];
    const float* w_l2 = (const float*)d_in[5];
    const float* b_l2 = (const float*)d_in[6];
    const float* w_c  = (const float*)d_in[7];
    const float* b_c  = (const float*)d_in[8];
    const float* w_f1 = (const float*)d_in[9];
    const float* b_f1 = (const float*)d_in[10];
    const float* w_f2 = (const float*)d_in[11];
    const float* b_f2 = (const float*)d_in[12];
    const float* w_f3 = (const float*)d_in[13];
    const float* b_f3 = (const float*)d_in[14];

    // Workspace (ushort offsets):
    //   xbu (2 parities) @0: 4,073,472
    //   h0A | h1A | h0B | h1B: 16,367,616
    //   cst fp16: 5,120,000
    //   Wfrag 442,368 | Wc 73,728 | f1 8,192  -> total ~26.1M ush = 52.2 MB
    //   tail aliases: Hc -> h0B/h1B (dead); conv_out -> cst (dead); pool -> xbu (dead).
    ushort_t* wsu = (ushort_t*)d_ws;
    uint_t*   wsi = (uint_t*)d_ws;

    ushort_t* xbu = wsu;                          // 2 * XBUT
    ushort_t* h0A = xbu + 2 * (size_t)XBUT;
    ushort_t* h1A = h0A + HB0T;
    ushort_t* h0B = h1A + HB1T;
    ushort_t* h1B = h0B + HB0T;
    ushort_t* cst = h1B + HB1T;                   // 5,120,000 ush (fp16 c)
    ushort_t* Wfrag = cst + 5120000;
    ushort_t* Wc    = Wfrag + WFRAG_TOT;
    float*    f1    = (float*)(Wc + 73728);
    ushort_t* Hc    = h0B;
    float*    conv_out = (float*)cst;
    float*    pool  = (float*)wsu;

    // zero x-buf (both parities, borders) + h-bufs (borders + h0 state)
    const size_t zt = 2 * (size_t)XBUT + 2 * (size_t)HPART;
    fill_zero_kernel<<<((int)(zt / 2) + 255) / 256, 256, 0, stream>>>(wsi, (int)(zt / 2));
    repack_w_kernel<<<(WFRAG_TOT + 255) / 256, 256, 0, stream>>>(w_l1, w_l2, Wfrag);
    repack_wc_kernel<<<(9 * 64 * 128 + 255) / 256, 256, 0, stream>>>(w_c, Wc);

    // LN for t=0 into parity-0 x-buf
    ln_t_kernel<<<(B_ * NPIX + 255) / 256, 256, 0, stream>>>(x, ln_g, ln_b, xbu, 0);

    ushort_t* H0[2] = {h0A, h0B};
    ushort_t* H1[2] = {h1A, h1B};
    for (int t = 0; t < T_; ++t) {
        const int cur = t & 1, nxt = cur ^ 1;
        convlstm_mfma_kernel<<<dim3(NRG, B_, 2), 512, 0, stream>>>(
            x, ln_g, ln_b, xbu,
            H0[cur], H1[cur], H0[nxt], H1[nxt], Wfrag, b_l1, b_l2, cst, t);
    }
    // final h in parity-0 (A). Hc overwrites dead B half: zero it first.
    fill_zero_kernel<<<(HCTOT / 2 + 255) / 256, 256, 0, stream>>>((uint_t*)Hc, HCTOT / 2);
    combine_h_kernel<<<(B_ * NPIX * 128 + 255) / 256, 256, 0, stream>>>(h0A, h1A, Hc);
    conv_mfma_kernel<<<dim3(7, B_), 512, 0, stream>>>(Hc, Wc, b_c, conv_out);
    pool_kernel<<<(B_ * 64 * 144 + 255) / 256, 256, 0, stream>>>(conv_out, pool);
    fc1_kernel<<<1024, 256, 0, stream>>>(pool, w_f1, b_f1, f1);
    head2_kernel<<<B_, 64, 0, stream>>>(f1, w_f2, b_f2, w_f3, b_f3, (float*)d_out);
}

// Round 19
// 1905.646 us; speedup vs baseline: 1.1741x; 1.1741x over previous
//
#include <hip/hip_runtime.h>
#include <hip/hip_bf16.h>
#include <math.h>

#define B_    64
#define T_    24
#define IND_  25
#define HID_  64
#define NPIX  625

// padded-grid geometry
#define WP0   27
#define WP1   29
#define HSTR  72          // h-buf pixel stride (ushorts)
#define HROWS0 800
#define HROWS1 912
#define HB0   (HROWS0*HSTR)
#define HB1   (HROWS1*HSTR)
#define HB0T  (B_*HB0)
#define HB1T  (B_*HB1)
#define HPART (HB0T+HB1T)

// universal x buffer: 2-halo 29-wide grid, row stride padded to 936 ush
// (1872B = 468 dwords; 468%32=20 -> b128 lane starts cover all 32 banks)
#define WPX   29
#define XRW   936
#define XROWSU 34
#define XBU   (XROWSU*XRW)    // 31,824 ush per (par,b)
#define XBUT  (B_*XBU)        // 2,036,736 per parity

// 3-row rowgroups
#define NRG   9
#define RST0  144
#define RST1  212
#define CH0   (RST0*9)    // 1296  h chunks
#define CH1   (RST1*9)    // 1908
#define XTROWS 8
#define XTCH  (XTROWS*XRW/8)  // 936 x chunks

// final-conv combined input: [b][832 rows][128] bf16
#define HCROWS 832
#define HCB    (HCROWS*128)
#define HCTOT  (B_*HCB)

#define WFRAG_PER_BR (9*3*4*4*512)    // 221,184
#define WFRAG_TOT    (2*WFRAG_PER_BR)

typedef __bf16 bf16x8 __attribute__((ext_vector_type(8)));
typedef float  f32x4  __attribute__((ext_vector_type(4)));
typedef _Float16 f16x4 __attribute__((ext_vector_type(4)));
typedef unsigned short ushort_t;
typedef unsigned int   uint_t;

typedef const __attribute__((address_space(1))) void as1_cvoid;
typedef __attribute__((address_space(3))) void as3_void;

__device__ __forceinline__ float sigmoidf_(float x) { return 1.f / (1.f + __expf(-x)); }
__device__ __forceinline__ float tanh_fast(float x) { return 2.f / (1.f + __expf(-2.f * x)) - 1.f; }
__device__ __forceinline__ ushort_t f2bf(float f) {
    unsigned int u = __float_as_uint(f);
    u += 0x7FFFu + ((u >> 16) & 1u);
    return (ushort_t)(u >> 16);
}

__global__ __launch_bounds__(256) void fill_zero_kernel(uint_t* __restrict__ p, int n) {
    int i = blockIdx.x * 256 + threadIdx.x;
    if (i < n) p[i] = 0u;
}

// Wfrag[br][tap][kk][wm][mf][lane][e]: m = wm*64 + gate*16 + ocl, gate=mf, oc=wm*16+l16.
__global__ __launch_bounds__(256) void repack_w_kernel(
    const float* __restrict__ w1, const float* __restrict__ w2, ushort_t* __restrict__ Wfrag)
{
    int id = blockIdx.x * 256 + threadIdx.x;
    if (id >= WFRAG_TOT) return;
    int e    = id & 7;
    int lane = (id >> 3) & 63;
    int mf   = (id >> 9) & 3;
    int wm   = (id >> 11) & 3;
    int rest = id >> 13;
    int kk   = rest % 3;
    int tap  = (rest / 3) % 9;
    int br   = rest / 27;
    int l16 = lane & 15, kh = lane >> 4;
    int gate = mf;
    int oc   = wm * 16 + l16;
    int k    = kh * 8 + e;
    int c;
    if (kk == 0)      c = (k < IND_) ? k : -1;
    else if (kk == 1) c = IND_ + k;
    else              c = IND_ + 32 + k;
    const float* w = br ? w2 : w1;
    float v = (c >= 0) ? w[((size_t)(gate * 64 + oc) * 89 + c) * 9 + tap] : 0.f;
    Wfrag[id] = f2bf(v);
}

__global__ __launch_bounds__(256) void repack_wc_kernel(
    const float* __restrict__ wc, ushort_t* __restrict__ Wc)
{
    int id = blockIdx.x * 256 + threadIdx.x;
    if (id >= 9 * 64 * 128) return;
    int k   = id % 128;
    int oc  = (id / 128) % 64;
    int tap = id / (128 * 64);
    Wc[id] = f2bf(wc[((size_t)(oc * 128) + k) * 9 + tap]);
}

// Standalone LN (only for t = 0; writes parity-0 universal x-buf).
__global__ __launch_bounds__(256) void ln_t_kernel(
    const float* __restrict__ x, const float* __restrict__ gamma, const float* __restrict__ beta,
    ushort_t* __restrict__ xbu, int t)
{
    int p = blockIdx.x * 256 + threadIdx.x;
    if (p >= B_ * NPIX) return;
    int b = p / NPIX, hw = p % NPIX;
    int y = hw / 25, xx = hw % 25;
    const float* xp = x + ((size_t)(b * T_ + t) * IND_) * NPIX + hw;
    float v[IND_];
    float s = 0.f;
#pragma unroll
    for (int c = 0; c < IND_; ++c) { v[c] = xp[c * NPIX]; s += v[c]; }
    float mu = s * (1.f / IND_);
    float ss = 0.f;
#pragma unroll
    for (int c = 0; c < IND_; ++c) { float d = v[c] - mu; ss += d * d; }
    float rstd = rsqrtf(ss * (1.f / IND_) + 1e-5f);
    ushort_t* o = xbu + (size_t)b * XBU + (size_t)(y + 2) * XRW + (size_t)(xx + 2) * 32;
#pragma unroll
    for (int c = 0; c < IND_; ++c)
        o[c] = f2bf((v[c] - mu) * rstd * gamma[c] + beta[c]);
}

// One ConvLSTM timestep, both branches. h+x tiles in LDS (coherent staging),
// fused LN(t+1), fp16 c, DEPTH=2 A-fragment ping-pong (proven R12 scheme).
__global__ __launch_bounds__(512, 4) void convlstm_mfma_kernel(
    const float* __restrict__ x, const float* __restrict__ ln_g, const float* __restrict__ ln_b,
    ushort_t* __restrict__ xbu,
    const ushort_t* __restrict__ h0c, const ushort_t* __restrict__ h1c,
    ushort_t* __restrict__ h0n, ushort_t* __restrict__ h1n,
    const ushort_t* __restrict__ Wfrag,
    const float* __restrict__ bias1, const float* __restrict__ bias2,
    ushort_t* __restrict__ cst, int t)
{
    const int rg = blockIdx.x;
    const int b  = blockIdx.y;
    const int br = blockIdx.z;
    const int d  = 1 + br;
    const int Wp = 25 + 2 * d;
    const int par = t & 1, nxt = par ^ 1;
    const ushort_t* __restrict__ hc = (br ? h1c + (size_t)b * HB1 : h0c + (size_t)b * HB0);
    ushort_t* __restrict__ hn       = (br ? h1n + (size_t)b * HB1 : h0n + (size_t)b * HB0);
    const float* __restrict__ bias = br ? bias2 : bias1;
    const ushort_t* __restrict__ WFb = Wfrag + (size_t)br * WFRAG_PER_BR;
    f16x4* __restrict__ cb4 = (f16x4*)cst + (size_t)(br * B_ + b) * 16 * NPIX;

    __shared__ ushort_t tile[RST1 * HSTR];    // 30,528 B
    __shared__ ushort_t xt[XTROWS * XRW];     // 14,976 B

    const int tid = threadIdx.x;
    const int u0  = rg * 3 * Wp;
    const int CH  = br ? CH1 : CH0;
    const int wave_u = tid & 448;

    // ---- async stage h-tile (linear 16B chunks)
    {
        const char* gsrc = (const char*)(hc + (size_t)u0 * HSTR);
#pragma unroll
        for (int j = 0; j < 4; ++j) {
            const int i = j * 512 + tid;
            if (i < CH) {
                __builtin_amdgcn_global_load_lds(
                    (as1_cvoid*)(gsrc + (size_t)i * 16),
                    (as3_void*)((char*)tile + (size_t)(j * 512 + wave_u) * 16),
                    16, 0, 0);
            }
        }
    }
    // ---- async stage x-tile (8 universal rows, linear)
    {
        const char* gsrc = (const char*)(xbu + (size_t)par * XBUT + (size_t)b * XBU
                                         + (size_t)(rg * 3) * XRW);
#pragma unroll
        for (int j = 0; j < 2; ++j) {
            const int i = j * 512 + tid;
            if (i < XTCH) {
                __builtin_amdgcn_global_load_lds(
                    (as1_cvoid*)(gsrc + (size_t)i * 16),
                    (as3_void*)((char*)xt + (size_t)(j * 512 + wave_u) * 16),
                    16, 0, 0);
            }
        }
    }
    // ---- fused LN for step t+1 (single universal write; overlaps stage drain)
    if (t + 1 < T_ && tid < 35) {
        const int linbid = (br * B_ + b) * NRG + rg;
        const int p = linbid * 35 + tid;
        if (p < B_ * NPIX) {
            const int bb = p / NPIX, hw = p - bb * NPIX;
            const int y = hw / 25, xx = hw - y * 25;
            const float* xp = x + ((size_t)(bb * T_ + t + 1) * IND_) * NPIX + hw;
            float v[IND_];
            float s = 0.f;
#pragma unroll
            for (int c = 0; c < IND_; ++c) { v[c] = xp[c * NPIX]; s += v[c]; }
            const float mu = s * (1.f / IND_);
            float ss = 0.f;
#pragma unroll
            for (int c = 0; c < IND_; ++c) { float dd = v[c] - mu; ss += dd * dd; }
            const float rstd = rsqrtf(ss * (1.f / IND_) + 1e-5f);
            ushort_t us[IND_];
#pragma unroll
            for (int c = 0; c < IND_; ++c) us[c] = f2bf((v[c] - mu) * rstd * ln_g[c] + ln_b[c]);
            uint4 q0, q1, q2;
            q0.x = us[0] | ((uint_t)us[1] << 16);   q0.y = us[2] | ((uint_t)us[3] << 16);
            q0.z = us[4] | ((uint_t)us[5] << 16);   q0.w = us[6] | ((uint_t)us[7] << 16);
            q1.x = us[8] | ((uint_t)us[9] << 16);   q1.y = us[10] | ((uint_t)us[11] << 16);
            q1.z = us[12] | ((uint_t)us[13] << 16); q1.w = us[14] | ((uint_t)us[15] << 16);
            q2.x = us[16] | ((uint_t)us[17] << 16); q2.y = us[18] | ((uint_t)us[19] << 16);
            q2.z = us[20] | ((uint_t)us[21] << 16); q2.w = us[22] | ((uint_t)us[23] << 16);
            ushort_t* o = xbu + (size_t)nxt * XBUT + (size_t)bb * XBU
                          + (size_t)(y + 2) * XRW + (size_t)(xx + 2) * 32;
            *(uint4*)o = q0; *(uint4*)(o + 8) = q1; *(uint4*)(o + 16) = q2; o[24] = us[24];
        }
    }
    __syncthreads();

    const int w    = tid >> 6, lane = tid & 63;
    const int wm   = w & 3, wn = w >> 2;
    const int l16  = lane & 15, kh = lane >> 4;
    const int koff = kh * 8;

    f32x4 acc[4][3];
#pragma unroll
    for (int i = 0; i < 4; ++i)
#pragma unroll
        for (int j = 0; j < 3; ++j) acc[i][j] = (f32x4){0.f, 0.f, 0.f, 0.f};

    int baserel[3];   // h-tile relative (tile rows, width Wp)
    int basexl[3];    // x-tile relative (stride XRW), elem units
#pragma unroll
    for (int nf = 0; nf < 3; ++nf) {
        int n = wn * 48 + nf * 16 + l16;
        const int rit = n >> 5, xxa = n & 31;
        baserel[nf] = rit * Wp + xxa;
        basexl[nf]  = (rit + 2) * XRW + (xxa + 2) * 32 + koff;
    }

    // DEPTH=2 A-fragment ping-pong over linearized u = tap*3+kk (prefetch distance 1
    // < depth 2, no aliasing).
    const ushort_t* __restrict__ WTb = WFb + wm * 2048 + lane * 8;
    bf16x8 af[2][4];
#pragma unroll
    for (int mf = 0; mf < 4; ++mf)
        af[0][mf] = *(const bf16x8*)(WTb + mf * 512);

#pragma unroll
    for (int u = 0; u < 27; ++u) {
        if (u + 1 < 27) {
#pragma unroll
            for (int mf = 0; mf < 4; ++mf)
                af[(u + 1) & 1][mf] =
                    *(const bf16x8*)(WTb + (size_t)(u + 1) * 8192 + mf * 512);
        }
        const int tap = u / 3, kk = u - 3 * (u / 3);
        const int ky = tap / 3, kx = tap - 3 * ky;
        bf16x8 bfr[3];
        if (kk == 0) {
            const int toffx = ((ky - 1) * d) * XRW + ((kx - 1) * d) * 32;
#pragma unroll
            for (int nf = 0; nf < 3; ++nf)
                bfr[nf] = *(const bf16x8*)(xt + (size_t)(basexl[nf] + toffx));
        } else {
            const int toff = (ky * Wp + kx) * d;
#pragma unroll
            for (int nf = 0; nf < 3; ++nf)
                bfr[nf] = *(const bf16x8*)(tile + (baserel[nf] + toff) * HSTR
                                           + (kk - 1) * 32 + koff);
        }
#pragma unroll
        for (int mf = 0; mf < 4; ++mf)
#pragma unroll
            for (int nf = 0; nf < 3; ++nf)
                acc[mf][nf] = __builtin_amdgcn_mfma_f32_16x16x32_bf16(
                    af[u & 1][mf], bfr[nf], acc[mf][nf], 0, 0, 0);
    }

    // Epilogue (c in fp16; bias loaded after the MFMA loop).
    const int oc0 = wm * 16 + kh * 4;
    const int ocq = wm * 4 + kh;
    float bi4[4], bf4[4], bo4[4], bg4[4];
#pragma unroll
    for (int r = 0; r < 4; ++r) {
        bi4[r] = bias[oc0 + r];
        bf4[r] = bias[64 + oc0 + r];
        bo4[r] = bias[128 + oc0 + r];
        bg4[r] = bias[192 + oc0 + r];
    }
#pragma unroll
    for (int nf = 0; nf < 3; ++nf) {
        const int n = wn * 48 + nf * 16 + l16;
        const int xx = n & 31;
        if (xx >= 25) continue;
        const int y = rg * 3 + (n >> 5);
        if (y >= 25) continue;
        const int pix = y * 25 + xx;
        f16x4* cp = cb4 + (size_t)ocq * NPIX + pix;
        f16x4 cvh;
        if (t != 0) cvh = *cp;
        else        cvh = (f16x4){0, 0, 0, 0};
        ushort_t hs[4];
#pragma unroll
        for (int r = 0; r < 4; ++r) {
            const float zi = acc[0][nf][r] + bi4[r];
            const float zf = acc[1][nf][r] + bf4[r];
            const float zo = acc[2][nf][r] + bo4[r];
            const float zg = acc[3][nf][r] + bg4[r];
            const float cn = sigmoidf_(zf) * (float)cvh[r] + sigmoidf_(zi) * tanh_fast(zg);
            cvh[r] = (_Float16)cn;
            hs[r] = f2bf(sigmoidf_(zo) * tanh_fast(cn));
        }
        *cp = cvh;
        uint2 hv;
        hv.x = (uint_t)hs[0] | ((uint_t)hs[1] << 16);
        hv.y = (uint_t)hs[2] | ((uint_t)hs[3] << 16);
        *(uint2*)(hn + (size_t)((y + d) * Wp + (xx + d)) * HSTR + oc0) = hv;
    }
}

// Combine final hidden states into Hc[b][(y+1)*27+(x+1)][k=128] bf16.
__global__ __launch_bounds__(256) void combine_h_kernel(
    const ushort_t* __restrict__ h0, const ushort_t* __restrict__ h1, ushort_t* __restrict__ Hc)
{
    int id = blockIdx.x * 256 + threadIdx.x;
    if (id >= B_ * NPIX * 128) return;
    int k   = id % 128;
    int pix = (id / 128) % NPIX;
    int b   = id / (128 * NPIX);
    int y = pix / 25, xx = pix % 25;
    ushort_t v;
    if (k < 64) v = h0[(size_t)b * HB0 + (size_t)((y + 1) * WP0 + (xx + 1)) * HSTR + k];
    else        v = h1[(size_t)b * HB1 + (size_t)((y + 2) * WP1 + (xx + 2)) * HSTR + (k - 64)];
    Hc[(size_t)b * HCB + (size_t)((y + 1) * 27 + (xx + 1)) * 128 + k] = v;
}

// Final 3x3 conv (128->64, pad 1) + bias + ReLU via MFMA implicit-GEMM.
__global__ __launch_bounds__(512) void conv_mfma_kernel(
    const ushort_t* __restrict__ Hc, const ushort_t* __restrict__ Wc,
    const float* __restrict__ bc, float* __restrict__ conv_out)
{
    const int rg = blockIdx.x;
    const int b  = blockIdx.y;
    const ushort_t* __restrict__ Hb = Hc + (size_t)b * HCB;

    const int tid  = threadIdx.x;
    const int w    = tid >> 6, lane = tid & 63;
    const int wm   = w & 1, wn = w >> 1;
    const int l16  = lane & 15, kh = lane >> 4;
    const int koff = kh * 8;

    f32x4 acc[2][2];
#pragma unroll
    for (int i = 0; i < 2; ++i)
#pragma unroll
        for (int j = 0; j < 2; ++j) acc[i][j] = (f32x4){0.f, 0.f, 0.f, 0.f};

    int baserow[2];
#pragma unroll
    for (int nf = 0; nf < 2; ++nf) {
        int n = wn * 32 + nf * 16 + l16;
        baserow[nf] = (rg * 4 + (n >> 5)) * 27 + (n & 31);
    }
    const ushort_t* __restrict__ Wm = Wc + (size_t)(wm * 32 + l16) * 128 + koff;

    for (int tap = 0; tap < 9; ++tap) {
        const int ky = tap / 3, kx = tap - 3 * ky;
        const int toff = ky * 27 + kx;
        const ushort_t* __restrict__ Wt = Wm + (size_t)tap * (64 * 128);
        const ushort_t* Urow[2];
#pragma unroll
        for (int nf = 0; nf < 2; ++nf)
            Urow[nf] = Hb + (size_t)(baserow[nf] + toff) * 128 + koff;
#pragma unroll
        for (int kk = 0; kk < 4; ++kk) {
            bf16x8 af[2], bfr[2];
#pragma unroll
            for (int mf = 0; mf < 2; ++mf)
                af[mf] = *(const bf16x8*)(Wt + mf * 16 * 128 + kk * 32);
#pragma unroll
            for (int nf = 0; nf < 2; ++nf)
                bfr[nf] = *(const bf16x8*)(Urow[nf] + kk * 32);
#pragma unroll
            for (int mf = 0; mf < 2; ++mf)
#pragma unroll
                for (int nf = 0; nf < 2; ++nf)
                    acc[mf][nf] = __builtin_amdgcn_mfma_f32_16x16x32_bf16(
                        af[mf], bfr[nf], acc[mf][nf], 0, 0, 0);
        }
    }

#pragma unroll
    for (int mf = 0; mf < 2; ++mf) {
#pragma unroll
        for (int nf = 0; nf < 2; ++nf) {
            const int n = wn * 32 + nf * 16 + l16;
            const int xx = n & 31;
            if (xx >= 25) continue;
            const int y = rg * 4 + wn;
            if (y >= 25) continue;
#pragma unroll
            for (int r = 0; r < 4; ++r) {
                const int oc = wm * 32 + mf * 16 + kh * 4 + r;
                const float v = fmaxf(acc[mf][nf][r] + bc[oc], 0.f);
                conv_out[((size_t)(b * 64 + oc)) * NPIX + y * 25 + xx] = v;
            }
        }
    }
}

__global__ __launch_bounds__(256) void pool_kernel(
    const float* __restrict__ conv_out, float* __restrict__ pool)
{
    int id = blockIdx.x * 256 + threadIdx.x;
    if (id >= B_ * 64 * 144) return;
    int px = id % 12;
    int py = (id / 12) % 12;
    int oc = (id / 144) % 64;
    int b  = id / (144 * 64);
    const float* p = conv_out + ((size_t)(b * 64 + oc)) * NPIX;
    const int cy = 2 * py, cx = 2 * px;
    float mx = fmaxf(fmaxf(p[cy * 25 + cx], p[cy * 25 + cx + 1]),
                     fmaxf(p[(cy + 1) * 25 + cx], p[(cy + 1) * 25 + cx + 1]));
    pool[(size_t)b * 9216 + oc * 144 + py * 12 + px] = mx;
}

__global__ __launch_bounds__(256) void fc1_kernel(
    const float* __restrict__ pool, const float* __restrict__ w1, const float* __restrict__ b1,
    float* __restrict__ f1)
{
    const int task = blockIdx.x * 4 + (threadIdx.x >> 6);
    const int lane = threadIdx.x & 63;
    const int b = task >> 6, oc = task & 63;
    const float* pr = pool + (size_t)b * 9216;
    const float* wr = w1 + (size_t)oc * 9216;
    float acc = 0.f;
#pragma unroll 4
    for (int it = 0; it < 36; ++it) {
        const int k = it * 256 + lane * 4;
        const float4 p = *(const float4*)(pr + k);
        const float4 ww = *(const float4*)(wr + k);
        acc += p.x * ww.x + p.y * ww.y + p.z * ww.z + p.w * ww.w;
    }
#pragma unroll
    for (int off = 32; off > 0; off >>= 1) acc += __shfl_down(acc, off);
    if (lane == 0) f1[b * 64 + oc] = fmaxf(acc + b1[oc], 0.f);
}

__global__ __launch_bounds__(64) void head2_kernel(
    const float* __restrict__ f1,
    const float* __restrict__ w2, const float* __restrict__ b2,
    const float* __restrict__ w3, const float* __restrict__ b3,
    float* __restrict__ out)
{
    const int b = blockIdx.x;
    __shared__ float f1l[64];
    __shared__ float f2[32];
    const int tid = threadIdx.x;
    f1l[tid] = f1[b * 64 + tid];
    __syncthreads();
    if (tid < 32) {
        float acc = b2[tid];
        const float* wr = w2 + (size_t)tid * 64;
#pragma unroll
        for (int k = 0; k < 64; ++k) acc += f1l[k] * wr[k];
        f2[tid] = fmaxf(acc, 0.f);
    }
    __syncthreads();
    if (tid == 0) {
        float y0 = b3[0], y1 = b3[1];
#pragma unroll
        for (int k = 0; k < 32; ++k) { y0 += f2[k] * w3[k]; y1 += f2[k] * w3[32 + k]; }
        const float m = fmaxf(y0, y1);
        const float lse = m + logf(expf(y0 - m) + expf(y1 - m));
        out[b * 2 + 0] = y0 - lse;
        out[b * 2 + 1] = y1 - lse;
    }
}

extern "C" void kernel_launch(void* const* d_in, const int* in_sizes, int n_in,
                              void* d_out, int out_size, void* d_ws, size_t ws_size,
                              hipStream_t stream) {
    const float* x    = (const float*)d_in[0];
    const float* ln_g = (const float*)d_in[1];
    const float* ln_b = (const float*)d_in[2];
    const float* w_l1 = (const float*)d_in[3];
    const float* b_l1 = (const float*)d_in[4];
    const float* w_l2 = (const float*)d_in[5];
    const float* b_l2 = (const float*)d_in[6];
    const float* w_c  = (const float*)d_in[7];
    const float* b_c  = (const float*)d_in[8];
    const float* w_f1 = (const float*)d_in[9];
    const float* b_f1 = (const float*)d_in[10];
    const float* w_f2 = (const float*)d_in[11];
    const float* b_f2 = (const float*)d_in[12];
    const float* w_f3 = (const float*)d_in[13];
    const float* b_f3 = (const float*)d_in[14];

    // Workspace (ushort offsets):
    //   xbu (2 parities) @0: 4,073,472
    //   h0A | h1A | h0B | h1B: 15,777,792
    //   cst fp16: 5,120,000
    //   Wfrag 442,368 | Wc 73,728 | f1 8,192  -> total ~25.5M ush = 51 MB
    //   tail aliases: Hc -> h0B/h1B (dead); conv_out -> cst (dead); pool -> xbu (dead).
    ushort_t* wsu = (ushort_t*)d_ws;
    uint_t*   wsi = (uint_t*)d_ws;

    ushort_t* xbu = wsu;                          // 2 * XBUT
    ushort_t* h0A = xbu + 2 * (size_t)XBUT;
    ushort_t* h1A = h0A + HB0T;
    ushort_t* h0B = h1A + HB1T;
    ushort_t* h1B = h0B + HB0T;
    ushort_t* cst = h1B + HB1T;                   // 5,120,000 ush (fp16 c)
    ushort_t* Wfrag = cst + 5120000;
    ushort_t* Wc    = Wfrag + WFRAG_TOT;
    float*    f1    = (float*)(Wc + 73728);
    ushort_t* Hc    = h0B;
    float*    conv_out = (float*)cst;
    float*    pool  = (float*)wsu;

    // zero x-buf (both parities, borders) + h-bufs (borders + h0 state)
    const size_t zt = 2 * (size_t)XBUT + 2 * (size_t)HPART;
    fill_zero_kernel<<<((int)(zt / 2) + 255) / 256, 256, 0, stream>>>(wsi, (int)(zt / 2));
    repack_w_kernel<<<(WFRAG_TOT + 255) / 256, 256, 0, stream>>>(w_l1, w_l2, Wfrag);
    repack_wc_kernel<<<(9 * 64 * 128 + 255) / 256, 256, 0, stream>>>(w_c, Wc);

    // LN for t=0 into parity-0 x-buf
    ln_t_kernel<<<(B_ * NPIX + 255) / 256, 256, 0, stream>>>(x, ln_g, ln_b, xbu, 0);

    ushort_t* H0[2] = {h0A, h0B};
    ushort_t* H1[2] = {h1A, h1B};
    for (int t = 0; t < T_; ++t) {
        const int cur = t & 1, nxt = cur ^ 1;
        convlstm_mfma_kernel<<<dim3(NRG, B_, 2), 512, 0, stream>>>(
            x, ln_g, ln_b, xbu,
            H0[cur], H1[cur], H0[nxt], H1[nxt], Wfrag, b_l1, b_l2, cst, t);
    }
    // final h in parity-0 (A). Hc overwrites dead B half: zero it first.
    fill_zero_kernel<<<(HCTOT / 2 + 255) / 256, 256, 0, stream>>>((uint_t*)Hc, HCTOT / 2);
    combine_h_kernel<<<(B_ * NPIX * 128 + 255) / 256, 256, 0, stream>>>(h0A, h1A, Hc);
    conv_mfma_kernel<<<dim3(7, B_), 512, 0, stream>>>(Hc, Wc, b_c, conv_out);
    pool_kernel<<<(B_ * 64 * 144 + 255) / 256, 256, 0, stream>>>(conv_out, pool);
    fc1_kernel<<<1024, 256, 0, stream>>>(pool, w_f1, b_f1, f1);
    head2_kernel<<<B_, 64, 0, stream>>>(f1, w_f2, b_f2, w_f3, b_f3, (float*)d_out);
}